// Round 4
// baseline (555.222 us; speedup 1.0000x reference)
//
#include <hip/hip_runtime.h>
#include <hip/hip_bf16.h>
#include <stdint.h>

#define TOKENS 4096
#define DDIM 1024
#define FDIM 4096
#define NEXP 8
#define BM 128
#define BN 128
#define BK2 32   // K-step; 4-slot LDS ring

typedef __attribute__((ext_vector_type(4))) float f32x4;
typedef __attribute__((ext_vector_type(8))) short short8;

__device__ __forceinline__ unsigned short f2bf(float f) {
    union { float f; uint32_t u; } v; v.f = f;
    uint32_t u = v.u;
    return (unsigned short)((u + 0x7fff + ((u >> 16) & 1)) >> 16);
}

#define BARRIER() asm volatile("s_barrier" ::: "memory")
#define WAIT_VM0() asm volatile("s_waitcnt vmcnt(0)" ::: "memory")
#define WAIT_VM4() asm volatile("s_waitcnt vmcnt(4)" ::: "memory")
#define WAIT_VM8() asm volatile("s_waitcnt vmcnt(8)" ::: "memory")
#define GLDS(SRC, DST) __builtin_amdgcn_global_load_lds( \
    (const __attribute__((address_space(1))) void*)(SRC), \
    (__attribute__((address_space(3))) void*)(DST), 16, 0, 0)

// ---------------- X f32 -> bf16 ----------------
__global__ __launch_bounds__(256) void cvt_x(const float* __restrict__ x,
                                             unsigned short* __restrict__ xb, int n) {
    int i = (blockIdx.x * 256 + threadIdx.x) * 8;
    if (i >= n) return;
    float4 a = *(const float4*)(x + i);
    float4 b = *(const float4*)(x + i + 4);
    short8 o;
    o[0] = f2bf(a.x); o[1] = f2bf(a.y); o[2] = f2bf(a.z); o[3] = f2bf(a.w);
    o[4] = f2bf(b.x); o[5] = f2bf(b.y); o[6] = f2bf(b.z); o[7] = f2bf(b.w);
    *(short8*)(xb + i) = o;
}

// ------------- transpose + cvt: in [E][R][C] f32 -> out [E][C][R] bf16 -------------
__global__ __launch_bounds__(256) void transpose_cvt(const float* __restrict__ in,
                                                     unsigned short* __restrict__ out,
                                                     int R, int C) {
    __shared__ float tile[32][33];
    int e = blockIdx.z;
    int r0 = blockIdx.y * 32, c0 = blockIdx.x * 32;
    const float* src = in + (size_t)e * R * C;
    unsigned short* dst = out + (size_t)e * R * C;
    int t = threadIdx.x;
    int rr = t >> 3;
    int cc = (t & 7) * 4;
    float4 v = *(const float4*)(src + (size_t)(r0 + rr) * C + c0 + cc);
    tile[rr][cc + 0] = v.x; tile[rr][cc + 1] = v.y;
    tile[rr][cc + 2] = v.z; tile[rr][cc + 3] = v.w;
    __syncthreads();
    int oc = rr;
    int orr = cc;
    ushort4 o;
    o.x = f2bf(tile[orr + 0][oc]);
    o.y = f2bf(tile[orr + 1][oc]);
    o.z = f2bf(tile[orr + 2][oc]);
    o.w = f2bf(tile[orr + 3][oc]);
    *(ushort4*)(dst + (size_t)(c0 + oc) * R + r0 + orr) = o;
}

// ---------------- router: top-2 of 8 logits, build expert lists ----------------
__global__ __launch_bounds__(256) void router(const float* __restrict__ x,
                                              const float* __restrict__ wr,
                                              int* __restrict__ cnt,
                                              int* __restrict__ list) {
    __shared__ float wl[NEXP * DDIM];
    int t = threadIdx.x;
    for (int i = t; i < NEXP * DDIM; i += 256) wl[i] = wr[i];
    __syncthreads();
    int tok = blockIdx.x * 4 + (t >> 6);
    int lane = t & 63;
    float acc[NEXP];
#pragma unroll
    for (int e = 0; e < NEXP; e++) acc[e] = 0.f;
    const float* xr = x + (size_t)tok * DDIM;
    for (int d = lane; d < DDIM; d += 64) {
        float xv = xr[d];
#pragma unroll
        for (int e = 0; e < NEXP; e++) acc[e] += xv * wl[e * DDIM + d];
    }
#pragma unroll
    for (int e = 0; e < NEXP; e++) {
#pragma unroll
        for (int off = 32; off; off >>= 1) acc[e] += __shfl_xor(acc[e], off);
    }
    if (lane == 0) {
        int e1 = 0; float v1 = acc[0];
        for (int e = 1; e < NEXP; e++) if (acc[e] > v1) { v1 = acc[e]; e1 = e; }
        int e2 = -1; float v2 = -1e30f;
        for (int e = 0; e < NEXP; e++) if (e != e1 && acc[e] > v2) { v2 = acc[e]; e2 = e; }
        int p1 = atomicAdd(&cnt[e1], 1);
        list[e1 * TOKENS + p1] = tok;
        int p2 = atomicAdd(&cnt[e2], 1);
        list[e2 * TOKENS + p2] = tok;
    }
}

// ---------------- setup: offsets, per-pass work bases, totals, counters ----------------
__global__ void setup(const int* __restrict__ cnt, int* __restrict__ off,
                      int* __restrict__ wbA, int* __restrict__ wbB,
                      int* __restrict__ qctr, int* __restrict__ tot) {
    if (threadIdx.x == 0) {
        int s = 0, ta = 0, tb = 0;
        for (int e = 0; e < NEXP; e++) {
            off[e] = s; s += cnt[e];
            wbA[e] = ta; wbB[e] = tb;
            int nt = (cnt[e] + BM - 1) / BM;
            ta += nt * (FDIM / BN);
            tb += nt * (DDIM / BN);
        }
        wbA[NEXP] = ta; wbB[NEXP] = tb;
        tot[0] = ta; tot[1] = tb;
        qctr[0] = 0; qctr[1] = 0;
    }
}

// ---------------- persistent grouped GEMM, 3-deep pipeline ----------------
// C[M,N] = A[M,K]*Wt[e][N,K]^T. BM=BN=128, BK=32, 4-slot LDS ring (64 KB, 2 blk/CU),
// counted vmcnt(8): tile t+3 staged while computing tile t. XOR swizzle chunk^((row>>1)&3).
template <bool GATHER_A, bool SILU>
__global__ __launch_bounds__(256, 2) void gemm_moe4(
    const unsigned short* __restrict__ Abase,
    const unsigned short* __restrict__ Wt,      // [E][NDIM][KD] bf16
    const int* __restrict__ cnt, const int* __restrict__ off,
    const int* __restrict__ list,
    const int* __restrict__ wbase,
    int* __restrict__ qctr, const int* __restrict__ tot,
    unsigned short* __restrict__ Hout,          // SILU out, stride NDIM
    float* __restrict__ Yout,                   // atomic out, stride NDIM
    int KD, int NDIM) {
    __shared__ alignas(16) unsigned short As[4][BM * BK2];  // 4 x 8 KB
    __shared__ alignas(16) unsigned short Bs[4][BN * BK2];  // 4 x 8 KB
    __shared__ int wsh;

    int t = threadIdx.x;
    int lane = t & 63;
    int wid = t >> 6;
    int wm = wid >> 1, wn = wid & 1;
    int r16 = lane & 15, g = lane >> 4;
    const int total = *tot;

    // read: k-chunk G of ROW stored at position G ^ ((ROW>>1)&3); halfword idx
#define FRAG32(TILE, ROW, G) (*(const short8*)&(TILE)[(ROW) * BK2 + ((((G) ^ (((ROW) >> 1) & 3))) << 3)])

    for (;;) {
        if (t == 0) wsh = atomicAdd(qctr, 1);
        __syncthreads();
        int w = wsh;
        if (w >= total) break;

        // ---- decode work item ----
        int e = 0;
        while (e < NEXP - 1 && w >= wbase[e + 1]) e++;
        w -= wbase[e];
        int n_e = cnt[e];
        int ntm = (n_e + BM - 1) >> 7;
        int by = w / ntm;
        int mtile = w - by * ntm;
        int m0 = mtile * BM;
        int n0 = by * BN;
        int base = off[e];

        // ---- staging pointers: 2 A-chunks + 2 B-chunks of 16 B per thread per tile ----
        // slot c = i*256+t: row = c>>2, pos p = c&3; global chunk = p ^ ((row>>1)&3)
        const unsigned short* pA[2];
        const unsigned short* pB[2];
        int ldsOff[2];
#pragma unroll
        for (int i = 0; i < 2; i++) {
            int c = i * 256 + t;
            int row = c >> 2, p = c & 3;
            int cg = p ^ ((row >> 1) & 3);
            int arow = m0 + row; if (arow >= n_e) arow = n_e - 1;
            size_t grow = GATHER_A ? (size_t)list[e * TOKENS + arow] : (size_t)(base + arow);
            pA[i] = Abase + grow * (size_t)KD + (cg << 3);
            pB[i] = Wt + ((size_t)e * NDIM + n0 + row) * (size_t)KD + (cg << 3);
            ldsOff[i] = c * 16;
        }

        f32x4 acc[4][4];
#pragma unroll
        for (int i = 0; i < 4; i++)
#pragma unroll
            for (int j = 0; j < 4; j++) acc[i][j] = f32x4{0.f, 0.f, 0.f, 0.f};

        // ---- prologue: stage tiles 0,1,2 into slots 0,1,2 (12 GLDS) ----
#pragma unroll
        for (int s = 0; s < 3; ++s) {
#pragma unroll
            for (int i = 0; i < 2; i++) { GLDS(pA[i], (char*)As[s] + ldsOff[i]); pA[i] += BK2; }
#pragma unroll
            for (int i = 0; i < 2; i++) { GLDS(pB[i], (char*)Bs[s] + ldsOff[i]); pB[i] += BK2; }
        }
        WAIT_VM8();   // tile 0 (oldest 4) complete
        BARRIER();

        const int NT = KD / BK2;
        for (int tk = 0; tk < NT; ++tk) {
            const int rs = tk & 3;
            const unsigned short* Ac = As[rs];
            const unsigned short* Bc = Bs[rs];

            // issue stage for tile tk+3 into ring slot (tk+3)&3
            if (tk + 3 < NT) {
                const int ws_ = (tk + 3) & 3;
#pragma unroll
                for (int i = 0; i < 2; i++) { GLDS(pA[i], (char*)As[ws_] + ldsOff[i]); pA[i] += BK2; }
#pragma unroll
                for (int i = 0; i < 2; i++) { GLDS(pB[i], (char*)Bs[ws_] + ldsOff[i]); pB[i] += BK2; }
            }

            short8 a0, a1, a2, a3, b0, b1, b2, b3;
            a0 = FRAG32(Ac, wm * 64 + 0 * 16 + r16, g);
            a1 = FRAG32(Ac, wm * 64 + 1 * 16 + r16, g);
            a2 = FRAG32(Ac, wm * 64 + 2 * 16 + r16, g);
            a3 = FRAG32(Ac, wm * 64 + 3 * 16 + r16, g);
            b0 = FRAG32(Bc, wn * 64 + 0 * 16 + r16, g);
            b1 = FRAG32(Bc, wn * 64 + 1 * 16 + r16, g);
            b2 = FRAG32(Bc, wn * 64 + 2 * 16 + r16, g);
            b3 = FRAG32(Bc, wn * 64 + 3 * 16 + r16, g);
            __builtin_amdgcn_s_setprio(1);
            acc[0][0] = __builtin_amdgcn_mfma_f32_16x16x32_bf16(a0, b0, acc[0][0], 0, 0, 0);
            acc[0][1] = __builtin_amdgcn_mfma_f32_16x16x32_bf16(a0, b1, acc[0][1], 0, 0, 0);
            acc[0][2] = __builtin_amdgcn_mfma_f32_16x16x32_bf16(a0, b2, acc[0][2], 0, 0, 0);
            acc[0][3] = __builtin_amdgcn_mfma_f32_16x16x32_bf16(a0, b3, acc[0][3], 0, 0, 0);
            acc[1][0] = __builtin_amdgcn_mfma_f32_16x16x32_bf16(a1, b0, acc[1][0], 0, 0, 0);
            acc[1][1] = __builtin_amdgcn_mfma_f32_16x16x32_bf16(a1, b1, acc[1][1], 0, 0, 0);
            acc[1][2] = __builtin_amdgcn_mfma_f32_16x16x32_bf16(a1, b2, acc[1][2], 0, 0, 0);
            acc[1][3] = __builtin_amdgcn_mfma_f32_16x16x32_bf16(a1, b3, acc[1][3], 0, 0, 0);
            acc[2][0] = __builtin_amdgcn_mfma_f32_16x16x32_bf16(a2, b0, acc[2][0], 0, 0, 0);
            acc[2][1] = __builtin_amdgcn_mfma_f32_16x16x32_bf16(a2, b1, acc[2][1], 0, 0, 0);
            acc[2][2] = __builtin_amdgcn_mfma_f32_16x16x32_bf16(a2, b2, acc[2][2], 0, 0, 0);
            acc[2][3] = __builtin_amdgcn_mfma_f32_16x16x32_bf16(a2, b3, acc[2][3], 0, 0, 0);
            acc[3][0] = __builtin_amdgcn_mfma_f32_16x16x32_bf16(a3, b0, acc[3][0], 0, 0, 0);
            acc[3][1] = __builtin_amdgcn_mfma_f32_16x16x32_bf16(a3, b1, acc[3][1], 0, 0, 0);
            acc[3][2] = __builtin_amdgcn_mfma_f32_16x16x32_bf16(a3, b2, acc[3][2], 0, 0, 0);
            acc[3][3] = __builtin_amdgcn_mfma_f32_16x16x32_bf16(a3, b3, acc[3][3], 0, 0, 0);
            __builtin_amdgcn_s_setprio(0);

            // counted drain: guarantee tile tk+1's loads (ours; others' via same wait+barrier)
            if (tk + 1 < NT) {
                if (tk + 3 < NT)      WAIT_VM8();
                else if (tk + 2 < NT) WAIT_VM4();
                else                  WAIT_VM0();
                BARRIER();
            }
        }

        // ---- epilogue: row = m0+wm*64+mi*16+g*4+q; col = n0+wn*64+nj*16+r16 ----
#pragma unroll
        for (int mi = 0; mi < 4; ++mi) {
#pragma unroll
            for (int nj = 0; nj < 4; ++nj) {
#pragma unroll
                for (int qq = 0; qq < 4; ++qq) {
                    int lr = wm * 64 + mi * 16 + g * 4 + qq;
                    if (m0 + lr < n_e) {
                        int col = n0 + wn * 64 + nj * 16 + r16;
                        float v = acc[mi][nj][qq];
                        if (SILU) {
                            v = v / (1.f + __expf(-v));
                            Hout[(size_t)(base + m0 + lr) * NDIM + col] = f2bf(v);
                        } else {
                            int tok = list[e * TOKENS + m0 + lr];
                            atomicAdd(&Yout[(size_t)tok * NDIM + col], v);
                        }
                    }
                }
            }
        }
    }
#undef FRAG32
}

extern "C" void kernel_launch(void* const* d_in, const int* in_sizes, int n_in,
                              void* d_out, int out_size, void* d_ws, size_t ws_size,
                              hipStream_t stream) {
    const float* X  = (const float*)d_in[0];
    const float* Wr = (const float*)d_in[1];
    const float* W1 = (const float*)d_in[2];
    const float* W2 = (const float*)d_in[3];
    float* Y = (float*)d_out;

    char* ws = (char*)d_ws;
    int* cnt  = (int*)(ws + 0);
    int* off  = (int*)(ws + 64);
    int* wbA  = (int*)(ws + 128);
    int* wbB  = (int*)(ws + 192);
    int* qctr = (int*)(ws + 256);
    int* tot  = (int*)(ws + 288);
    int* list = (int*)(ws + 1024);                               // 128 KB
    unsigned short* Xb = (unsigned short*)(ws + (1ull << 20));   // 8 MB
    unsigned short* WT = (unsigned short*)(ws + (16ull << 20));  // 64 MB (W1T, then W2T)
    unsigned short* H  = (unsigned short*)(ws + (80ull << 20));  // 64 MB

    hipMemsetAsync(d_out, 0, (size_t)out_size * sizeof(float), stream);
    hipMemsetAsync(cnt, 0, 32, stream);

    cvt_x<<<TOKENS * DDIM / (256 * 8), 256, 0, stream>>>(X, Xb, TOKENS * DDIM);
    router<<<TOKENS / 4, 256, 0, stream>>>(X, Wr, cnt, list);
    setup<<<1, 64, 0, stream>>>(cnt, off, wbA, wbB, qctr, tot);

    // W1 [E][D][F] -> W1T [E][F][D] bf16
    transpose_cvt<<<dim3(FDIM / 32, DDIM / 32, NEXP), 256, 0, stream>>>(W1, WT, DDIM, FDIM);
    // Pass A: H[slot][F] = silu(X[tok] @ W1[e])
    gemm_moe4<true, true><<<512, 256, 0, stream>>>(
        Xb, WT, cnt, off, list, wbA, qctr + 0, tot + 0, H, nullptr, DDIM, FDIM);

    // W2 [E][F][D] -> W2T [E][D][F] bf16 (reuses WT)
    transpose_cvt<<<dim3(DDIM / 32, FDIM / 32, NEXP), 256, 0, stream>>>(W2, WT, FDIM, DDIM);
    // Pass B: Y[tok][D] += H[slot] @ W2[e]
    gemm_moe4<false, false><<<512, 256, 0, stream>>>(
        H, WT, cnt, off, list, wbB, qctr + 1, tot + 1, nullptr, Y, FDIM, DDIM);
}

// Round 5
// 477.013 us; speedup vs baseline: 1.1640x; 1.1640x over previous
//
#include <hip/hip_runtime.h>
#include <hip/hip_bf16.h>
#include <stdint.h>

#define TOKENS 4096
#define DDIM 1024
#define FDIM 4096
#define NEXP 8
#define BM 128
#define BN 128
#define BK2 32   // K-step; 4-slot LDS ring

typedef __attribute__((ext_vector_type(4))) float f32x4;
typedef __attribute__((ext_vector_type(8))) short short8;

__device__ __forceinline__ unsigned short f2bf(float f) {
    union { float f; uint32_t u; } v; v.f = f;
    uint32_t u = v.u;
    return (unsigned short)((u + 0x7fff + ((u >> 16) & 1)) >> 16);
}

#define BARRIER() asm volatile("s_barrier" ::: "memory")
#define WAIT_VM0() asm volatile("s_waitcnt vmcnt(0)" ::: "memory")
#define WAIT_VM4() asm volatile("s_waitcnt vmcnt(4)" ::: "memory")
#define WAIT_VM8() asm volatile("s_waitcnt vmcnt(8)" ::: "memory")
#define WAIT_LGKM0() asm volatile("s_waitcnt lgkmcnt(0)" ::: "memory")
#define GLDS(SRC, DST) __builtin_amdgcn_global_load_lds( \
    (const __attribute__((address_space(1))) void*)(SRC), \
    (__attribute__((address_space(3))) void*)(DST), 16, 0, 0)

// inline-asm LDS read: compiler cannot see it -> no auto vmcnt(0) drains in loop
__device__ __forceinline__ short8 dsr(uint32_t addr) {
    short8 d;
    asm volatile("ds_read_b128 %0, %1" : "=v"(d) : "v"(addr));
    return d;
}

// ---------------- X f32 -> bf16 ----------------
__global__ __launch_bounds__(256) void cvt_x(const float* __restrict__ x,
                                             unsigned short* __restrict__ xb, int n) {
    int i = (blockIdx.x * 256 + threadIdx.x) * 8;
    if (i >= n) return;
    float4 a = *(const float4*)(x + i);
    float4 b = *(const float4*)(x + i + 4);
    short8 o;
    o[0] = f2bf(a.x); o[1] = f2bf(a.y); o[2] = f2bf(a.z); o[3] = f2bf(a.w);
    o[4] = f2bf(b.x); o[5] = f2bf(b.y); o[6] = f2bf(b.z); o[7] = f2bf(b.w);
    *(short8*)(xb + i) = o;
}

// ------------- transpose + cvt: in [E][R][C] f32 -> out [E][C][R] bf16 -------------
__global__ __launch_bounds__(256) void transpose_cvt(const float* __restrict__ in,
                                                     unsigned short* __restrict__ out,
                                                     int R, int C) {
    __shared__ float tile[32][33];
    int e = blockIdx.z;
    int r0 = blockIdx.y * 32, c0 = blockIdx.x * 32;
    const float* src = in + (size_t)e * R * C;
    unsigned short* dst = out + (size_t)e * R * C;
    int t = threadIdx.x;
    int rr = t >> 3;
    int cc = (t & 7) * 4;
    float4 v = *(const float4*)(src + (size_t)(r0 + rr) * C + c0 + cc);
    tile[rr][cc + 0] = v.x; tile[rr][cc + 1] = v.y;
    tile[rr][cc + 2] = v.z; tile[rr][cc + 3] = v.w;
    __syncthreads();
    int oc = rr;
    int orr = cc;
    ushort4 o;
    o.x = f2bf(tile[orr + 0][oc]);
    o.y = f2bf(tile[orr + 1][oc]);
    o.z = f2bf(tile[orr + 2][oc]);
    o.w = f2bf(tile[orr + 3][oc]);
    *(ushort4*)(dst + (size_t)(c0 + oc) * R + r0 + orr) = o;
}

// ---------------- router: top-2 of 8 logits, build expert lists ----------------
__global__ __launch_bounds__(256) void router(const float* __restrict__ x,
                                              const float* __restrict__ wr,
                                              int* __restrict__ cnt,
                                              int* __restrict__ list) {
    __shared__ float wl[NEXP * DDIM];
    int t = threadIdx.x;
    for (int i = t; i < NEXP * DDIM; i += 256) wl[i] = wr[i];
    __syncthreads();
    int tok = blockIdx.x * 4 + (t >> 6);
    int lane = t & 63;
    float acc[NEXP];
#pragma unroll
    for (int e = 0; e < NEXP; e++) acc[e] = 0.f;
    const float* xr = x + (size_t)tok * DDIM;
    for (int d = lane; d < DDIM; d += 64) {
        float xv = xr[d];
#pragma unroll
        for (int e = 0; e < NEXP; e++) acc[e] += xv * wl[e * DDIM + d];
    }
#pragma unroll
    for (int e = 0; e < NEXP; e++) {
#pragma unroll
        for (int off = 32; off; off >>= 1) acc[e] += __shfl_xor(acc[e], off);
    }
    if (lane == 0) {
        int e1 = 0; float v1 = acc[0];
        for (int e = 1; e < NEXP; e++) if (acc[e] > v1) { v1 = acc[e]; e1 = e; }
        int e2 = -1; float v2 = -1e30f;
        for (int e = 0; e < NEXP; e++) if (e != e1 && acc[e] > v2) { v2 = acc[e]; e2 = e; }
        int p1 = atomicAdd(&cnt[e1], 1);
        list[e1 * TOKENS + p1] = tok;
        int p2 = atomicAdd(&cnt[e2], 1);
        list[e2 * TOKENS + p2] = tok;
    }
}

// ---------------- setup ----------------
__global__ void setup(const int* __restrict__ cnt, int* __restrict__ off,
                      int* __restrict__ wbA, int* __restrict__ wbB,
                      int* __restrict__ qctr, int* __restrict__ tot) {
    if (threadIdx.x == 0) {
        int s = 0, ta = 0, tb = 0;
        for (int e = 0; e < NEXP; e++) {
            off[e] = s; s += cnt[e];
            wbA[e] = ta; wbB[e] = tb;
            int nt = (cnt[e] + BM - 1) / BM;
            ta += nt * (FDIM / BN);
            tb += nt * (DDIM / BN);
        }
        wbA[NEXP] = ta; wbB[NEXP] = tb;
        tot[0] = ta; tot[1] = tb;
        qctr[0] = 0; qctr[1] = 0;
    }
}

// ---------------- persistent grouped GEMM, 3-deep pipeline, asm ds_read ----------------
template <bool GATHER_A, bool SILU>
__global__ __launch_bounds__(256, 2) void gemm_moe5(
    const unsigned short* __restrict__ Abase,
    const unsigned short* __restrict__ Wt,      // [E][NDIM][KD] bf16
    const int* __restrict__ cnt, const int* __restrict__ off,
    const int* __restrict__ list,
    const int* __restrict__ wbase,
    int* __restrict__ qctr, const int* __restrict__ tot,
    unsigned short* __restrict__ Hout,          // SILU out, stride NDIM
    float* __restrict__ Yout,                   // atomic out, stride NDIM
    int KD, int NDIM) {
    __shared__ alignas(16) unsigned short As[4][BM * BK2];  // 4 x 8 KB (slot stride 8192 B)
    __shared__ alignas(16) unsigned short Bs[4][BN * BK2];  // 4 x 8 KB
    __shared__ int wsh;

    int t = threadIdx.x;
    int lane = t & 63;
    int wid = t >> 6;
    int wm = wid >> 1, wn = wid & 1;
    int r16 = lane & 15, g = lane >> 4;
    const int total = *tot;

    // precomputed LDS frag addresses (slot 0); swizzle: chunk stored at g^((row>>1)&3)
    uint32_t asBase = (uint32_t)(uintptr_t)&As[0][0];
    uint32_t bsBase = (uint32_t)(uintptr_t)&Bs[0][0];
    uint32_t aAdr[4], bAdr[4];
#pragma unroll
    for (int mi = 0; mi < 4; mi++) {
        int row = wm * 64 + mi * 16 + r16;
        aAdr[mi] = asBase + row * 64 + ((g ^ ((row >> 1) & 3)) << 4);
    }
#pragma unroll
    for (int nj = 0; nj < 4; nj++) {
        int row = wn * 64 + nj * 16 + r16;
        bAdr[nj] = bsBase + row * 64 + ((g ^ ((row >> 1) & 3)) << 4);
    }

    for (;;) {
        if (t == 0) wsh = atomicAdd(qctr, 1);
        __syncthreads();   // also drains previous work item's ds_reads/stores
        int w = wsh;
        if (w >= total) break;

        // ---- decode work item ----
        int e = 0;
        while (e < NEXP - 1 && w >= wbase[e + 1]) e++;
        w -= wbase[e];
        int n_e = cnt[e];
        int ntm = (n_e + BM - 1) >> 7;
        int by = w / ntm;
        int mtile = w - by * ntm;
        int m0 = mtile * BM;
        int n0 = by * BN;
        int base = off[e];

        // ---- staging pointers: 2 A + 2 B chunks of 16 B per thread per tile ----
        // slot c = i*256+t: row = c>>2, pos p = c&3; global chunk = p ^ ((row>>1)&3)
        const unsigned short* pA[2];
        const unsigned short* pB[2];
        int ldsOff[2];
#pragma unroll
        for (int i = 0; i < 2; i++) {
            int c = i * 256 + t;
            int row = c >> 2, p = c & 3;
            int cg = p ^ ((row >> 1) & 3);
            int arow = m0 + row; if (arow >= n_e) arow = n_e - 1;
            size_t grow = GATHER_A ? (size_t)list[e * TOKENS + arow] : (size_t)(base + arow);
            pA[i] = Abase + grow * (size_t)KD + (cg << 3);
            pB[i] = Wt + ((size_t)e * NDIM + n0 + row) * (size_t)KD + (cg << 3);
            ldsOff[i] = c * 16;
        }

        f32x4 acc[4][4];
#pragma unroll
        for (int i = 0; i < 4; i++)
#pragma unroll
            for (int j = 0; j < 4; j++) acc[i][j] = f32x4{0.f, 0.f, 0.f, 0.f};

        // ---- prologue: stage tiles 0,1,2 into slots 0,1,2 (12 GLDS/wave) ----
#pragma unroll
        for (int s = 0; s < 3; ++s) {
#pragma unroll
            for (int i = 0; i < 2; i++) { GLDS(pA[i], (char*)As[s] + ldsOff[i]); pA[i] += BK2; }
#pragma unroll
            for (int i = 0; i < 2; i++) { GLDS(pB[i], (char*)Bs[s] + ldsOff[i]); pB[i] += BK2; }
        }
        WAIT_VM8();   // tile 0 (oldest 4) complete
        BARRIER();

        const int NT = KD / BK2;
        for (int tk = 0; tk < NT; ++tk) {
            const uint32_t sb = (uint32_t)(tk & 3) << 13;  // ring-slot byte offset

            // issue stage for tile tk+3 into ring slot (tk+3)&3 (== slot of dead tile tk-1)
            if (tk + 3 < NT) {
                const int ws_ = (tk + 3) & 3;
#pragma unroll
                for (int i = 0; i < 2; i++) { GLDS(pA[i], (char*)As[ws_] + ldsOff[i]); pA[i] += BK2; }
#pragma unroll
                for (int i = 0; i < 2; i++) { GLDS(pB[i], (char*)Bs[ws_] + ldsOff[i]); pB[i] += BK2; }
            }

            // fragment loads: opaque asm ds_read_b128 (no compiler-inserted vmcnt drains)
            short8 a0 = dsr(aAdr[0] + sb);
            short8 a1 = dsr(aAdr[1] + sb);
            short8 a2 = dsr(aAdr[2] + sb);
            short8 a3 = dsr(aAdr[3] + sb);
            short8 b0 = dsr(bAdr[0] + sb);
            short8 b1 = dsr(bAdr[1] + sb);
            short8 b2 = dsr(bAdr[2] + sb);
            short8 b3 = dsr(bAdr[3] + sb);
            WAIT_LGKM0();
            __builtin_amdgcn_sched_barrier(0);   // rule #18: keep MFMAs below the wait

            __builtin_amdgcn_s_setprio(1);
            acc[0][0] = __builtin_amdgcn_mfma_f32_16x16x32_bf16(a0, b0, acc[0][0], 0, 0, 0);
            acc[0][1] = __builtin_amdgcn_mfma_f32_16x16x32_bf16(a0, b1, acc[0][1], 0, 0, 0);
            acc[0][2] = __builtin_amdgcn_mfma_f32_16x16x32_bf16(a0, b2, acc[0][2], 0, 0, 0);
            acc[0][3] = __builtin_amdgcn_mfma_f32_16x16x32_bf16(a0, b3, acc[0][3], 0, 0, 0);
            acc[1][0] = __builtin_amdgcn_mfma_f32_16x16x32_bf16(a1, b0, acc[1][0], 0, 0, 0);
            acc[1][1] = __builtin_amdgcn_mfma_f32_16x16x32_bf16(a1, b1, acc[1][1], 0, 0, 0);
            acc[1][2] = __builtin_amdgcn_mfma_f32_16x16x32_bf16(a1, b2, acc[1][2], 0, 0, 0);
            acc[1][3] = __builtin_amdgcn_mfma_f32_16x16x32_bf16(a1, b3, acc[1][3], 0, 0, 0);
            acc[2][0] = __builtin_amdgcn_mfma_f32_16x16x32_bf16(a2, b0, acc[2][0], 0, 0, 0);
            acc[2][1] = __builtin_amdgcn_mfma_f32_16x16x32_bf16(a2, b1, acc[2][1], 0, 0, 0);
            acc[2][2] = __builtin_amdgcn_mfma_f32_16x16x32_bf16(a2, b2, acc[2][2], 0, 0, 0);
            acc[2][3] = __builtin_amdgcn_mfma_f32_16x16x32_bf16(a2, b3, acc[2][3], 0, 0, 0);
            acc[3][0] = __builtin_amdgcn_mfma_f32_16x16x32_bf16(a3, b0, acc[3][0], 0, 0, 0);
            acc[3][1] = __builtin_amdgcn_mfma_f32_16x16x32_bf16(a3, b1, acc[3][1], 0, 0, 0);
            acc[3][2] = __builtin_amdgcn_mfma_f32_16x16x32_bf16(a3, b2, acc[3][2], 0, 0, 0);
            acc[3][3] = __builtin_amdgcn_mfma_f32_16x16x32_bf16(a3, b3, acc[3][3], 0, 0, 0);
            __builtin_amdgcn_s_setprio(0);

            // counted drain: only guarantee tile tk+1 is resident; keep 8 loads in flight
            if (tk + 1 < NT) {
                if (tk + 3 < NT)      WAIT_VM8();
                else if (tk + 2 < NT) WAIT_VM4();
                else                  WAIT_VM0();
                BARRIER();
            }
        }

        // ---- epilogue: row = m0+wm*64+mi*16+g*4+q; col = n0+wn*64+nj*16+r16 ----
#pragma unroll
        for (int mi = 0; mi < 4; ++mi) {
#pragma unroll
            for (int nj = 0; nj < 4; ++nj) {
#pragma unroll
                for (int qq = 0; qq < 4; ++qq) {
                    int lr = wm * 64 + mi * 16 + g * 4 + qq;
                    if (m0 + lr < n_e) {
                        int col = n0 + wn * 64 + nj * 16 + r16;
                        float v = acc[mi][nj][qq];
                        if (SILU) {
                            v = v / (1.f + __expf(-v));
                            Hout[(size_t)(base + m0 + lr) * NDIM + col] = f2bf(v);
                        } else {
                            int tok = list[e * TOKENS + m0 + lr];
                            atomicAdd(&Yout[(size_t)tok * NDIM + col], v);
                        }
                    }
                }
            }
        }
    }
}

extern "C" void kernel_launch(void* const* d_in, const int* in_sizes, int n_in,
                              void* d_out, int out_size, void* d_ws, size_t ws_size,
                              hipStream_t stream) {
    const float* X  = (const float*)d_in[0];
    const float* Wr = (const float*)d_in[1];
    const float* W1 = (const float*)d_in[2];
    const float* W2 = (const float*)d_in[3];
    float* Y = (float*)d_out;

    char* ws = (char*)d_ws;
    int* cnt  = (int*)(ws + 0);
    int* off  = (int*)(ws + 64);
    int* wbA  = (int*)(ws + 128);
    int* wbB  = (int*)(ws + 192);
    int* qctr = (int*)(ws + 256);
    int* tot  = (int*)(ws + 288);
    int* list = (int*)(ws + 1024);                               // 128 KB
    unsigned short* Xb = (unsigned short*)(ws + (1ull << 20));   // 8 MB
    unsigned short* WT = (unsigned short*)(ws + (16ull << 20));  // 64 MB (W1T, then W2T)
    unsigned short* H  = (unsigned short*)(ws + (80ull << 20));  // 64 MB

    hipMemsetAsync(d_out, 0, (size_t)out_size * sizeof(float), stream);
    hipMemsetAsync(cnt, 0, 32, stream);

    cvt_x<<<TOKENS * DDIM / (256 * 8), 256, 0, stream>>>(X, Xb, TOKENS * DDIM);
    router<<<TOKENS / 4, 256, 0, stream>>>(X, Wr, cnt, list);
    setup<<<1, 64, 0, stream>>>(cnt, off, wbA, wbB, qctr, tot);

    // W1 [E][D][F] -> W1T [E][F][D] bf16
    transpose_cvt<<<dim3(FDIM / 32, DDIM / 32, NEXP), 256, 0, stream>>>(W1, WT, DDIM, FDIM);
    // Pass A: H[slot][F] = silu(X[tok] @ W1[e])
    gemm_moe5<true, true><<<512, 256, 0, stream>>>(
        Xb, WT, cnt, off, list, wbA, qctr + 0, tot + 0, H, nullptr, DDIM, FDIM);

    // W2 [E][F][D] -> W2T [E][D][F] bf16 (reuses WT)
    transpose_cvt<<<dim3(DDIM / 32, FDIM / 32, NEXP), 256, 0, stream>>>(W2, WT, FDIM, DDIM);
    // Pass B: Y[tok][D] += H[slot] @ W2[e]
    gemm_moe5<false, false><<<512, 256, 0, stream>>>(
        H, WT, cnt, off, list, wbB, qctr + 1, tot + 1, nullptr, Y, FDIM, DDIM);
}